// Round 2
// baseline (366.862 us; speedup 1.0000x reference)
//
#include <hip/hip_runtime.h>
#include <math.h>

#define NTHREADS 256
#define NELEM    4096   // H*W
#define EPL      64     // elements per lane (4096 / 64 lanes)

// order-preserving float->uint map (ascending)
__device__ __forceinline__ unsigned f2ord(float f) {
    unsigned u = __float_as_uint(f);
    return (u & 0x80000000u) ? ~u : (u | 0x80000000u);
}
__device__ __forceinline__ float ord2f(unsigned k) {
    unsigned u = (k & 0x80000000u) ? (k ^ 0x80000000u) : ~k;
    return __uint_as_float(u);
}

// wave-wide count of keys <= t over all 64 lanes * EPL regs (uniform result)
__device__ __forceinline__ unsigned count_leq(const unsigned* k, unsigned t) {
    unsigned c = 0;
    #pragma unroll
    for (int j = 0; j < EPL; ++j) {
        c += (unsigned)__popcll(__ballot(k[j] <= t));  // v_cmp -> s_bcnt1 (scalar pipe)
    }
    return c;
}

// smallest key value t with count_leq(t) >= rank+1  == key of s[rank] (0-indexed)
__device__ __forceinline__ unsigned bisect(const unsigned* k, unsigned rank) {
    unsigned lo = 0u, hi = 0xFFFFFFFFu;
    #pragma unroll 1
    for (int it = 0; it < 32; ++it) {
        if (lo >= hi) break;
        unsigned mid = lo + ((hi - lo) >> 1);
        if (count_leq(k, mid) >= rank + 1u) hi = mid;
        else                                lo = mid + 1u;
    }
    return lo;
}

__global__ void __launch_bounds__(NTHREADS)
xsrelu_kernel(const float* __restrict__ x, const float* __restrict__ plogit,
              float* __restrict__ out, int C) {
    const int wave = threadIdx.x >> 6;
    const int lane = threadIdx.x & 63;
    const int row  = blockIdx.x * 4 + wave;   // one wave per row, 4 rows/block

    const float4* xr = (const float4*)(x + (size_t)row * NELEM);

    // Load row (coalesced float4), convert to ordered keys in registers.
    unsigned k[EPL];
    #pragma unroll
    for (int j = 0; j < EPL / 4; ++j) {
        float4 v = xr[j * 64 + lane];
        k[4 * j + 0] = f2ord(v.x);
        k[4 * j + 1] = f2ord(v.y);
        k[4 * j + 2] = f2ord(v.z);
        k[4 * j + 3] = f2ord(v.w);
    }

    // p0 drives the scalar rank indices; pc drives the interpolation.
    float p0 = 1.0f / (1.0f + expf(-plogit[0]));
    int c = row % C;
    float pc = 1.0f / (1.0f + expf(-plogit[c]));

    int kLow  = (int)((float)NELEM * (p0 - 0.02f));   // trunc == astype(int32)
    int kHigh = (int)((float)NELEM * (p0 + 0.02f));
    kLow  = min(max(kLow,  0), NELEM - 1);
    kHigh = min(max(kHigh, 0), NELEM - 1);

    unsigned keyLow  = bisect(k, (unsigned)kLow);
    unsigned keyHigh = bisect(k, (unsigned)kHigh);

    float xlow  = ord2f(keyLow);
    float xhigh = ord2f(keyHigh);
    float thr = xlow + (xhigh - xlow) * pc;

    // Epilogue: relu(x - thr), reconstruct floats from keys (saves 64 VGPRs).
    float4* outr = (float4*)(out + (size_t)row * NELEM);
    #pragma unroll
    for (int j = 0; j < EPL / 4; ++j) {
        float4 o;
        o.x = fmaxf(ord2f(k[4 * j + 0]) - thr, 0.0f);
        o.y = fmaxf(ord2f(k[4 * j + 1]) - thr, 0.0f);
        o.z = fmaxf(ord2f(k[4 * j + 2]) - thr, 0.0f);
        o.w = fmaxf(ord2f(k[4 * j + 3]) - thr, 0.0f);
        outr[j * 64 + lane] = o;
    }
}

extern "C" void kernel_launch(void* const* d_in, const int* in_sizes, int n_in,
                              void* d_out, int out_size, void* d_ws, size_t ws_size,
                              hipStream_t stream) {
    const float* x      = (const float*)d_in[0];
    const float* plogit = (const float*)d_in[1];
    float* out          = (float*)d_out;
    int C    = in_sizes[1];              // 256
    int rows = in_sizes[0] / NELEM;      // 8192
    xsrelu_kernel<<<rows / 4, NTHREADS, 0, stream>>>(x, plogit, out, C);
}